// Round 14
// baseline (471.249 us; speedup 1.0000x reference)
//
#include <hip/hip_runtime.h>
#include <hip/hip_fp16.h>

#define HID   256
#define NHEAD 4
#define DOUT  64
#define ADIM  74
#define KPAD_IN 96
#define LAYERS 3

typedef _Float16 half8 __attribute__((ext_vector_type(8)));
typedef _Float16 half4 __attribute__((ext_vector_type(4)));
typedef float f32x4 __attribute__((ext_vector_type(4)));

__device__ __forceinline__ void gload16(const void* g, void* l) {
  __builtin_amdgcn_global_load_lds((const __attribute__((address_space(1))) void*)g,
                                   (__attribute__((address_space(3))) void*)l, 16, 0, 0);
}

// -------- weight prep (all layers + input proj in one launch) --------------
__global__ void k_prep(const float* __restrict__ Ws, const float* __restrict__ Wd,
                       const float* __restrict__ Win,
                       _Float16* __restrict__ WT, _Float16* __restrict__ WTin) {
  int l = blockIdx.y;
  int id = blockIdx.x * 256 + threadIdx.x;
  if (l < LAYERS) {
    if (id >= 512 * HID) return;
    int n = id >> 8, k = id & 255;
    const float* W = (n < HID) ? (Ws + (size_t)l * HID * HID)
                               : (Wd + (size_t)l * HID * HID);
    int nn = (n < HID) ? n : (n - HID);
    WT[(size_t)l * 512 * HID + id] = (_Float16)W[k * HID + nn];
  } else {
    if (id >= HID * KPAD_IN) return;
    int n = id / KPAD_IN, k = id % KPAD_IN;
    WTin[id] = (_Float16)((k < ADIM) ? Win[k * HID + n] : 0.f);
  }
}

// ---- 2-pass epilogue: acc -> LDS f16 [64][136] -> coalesced 64B stores ----
__device__ __forceinline__ void gemm_epilogue2(
    f32x4 acc[4][4], char* smem, int t, int lane, int wm, int wn,
    int row0, int col0, int M,
    const float* bias0, const float* bias1,
    _Float16* outS, _Float16* outD)
{
  const float* bp = (col0 < HID) ? (bias0 + col0) : (bias1 + (col0 - HID));
  _Float16*    op = (col0 < HID) ? (outS + col0) : (outD + (col0 - HID));
  _Float16 (*C)[136] = (_Float16(*)[136])smem;   // 64 x 136 x 2B = 17408 B
  #pragma unroll
  for (int half = 0; half < 2; ++half) {
    __syncthreads();
    if (wm == half) {
      #pragma unroll
      for (int i = 0; i < 4; ++i) {
        #pragma unroll
        for (int j = 0; j < 4; ++j) {
          int lc = wn * 64 + j * 16 + (lane & 15);
          float bv = bp[lc];
          #pragma unroll
          for (int r = 0; r < 4; ++r) {
            int lr = i * 16 + (lane >> 4) * 4 + r;
            C[lr][lc] = (_Float16)(acc[i][j][r] + bv);
          }
        }
      }
    }
    __syncthreads();
    int lr = t >> 2, seg = t & 3;
    int grow = row0 + half * 64 + lr;
    if (grow < M) {
      const _Float16* sp = &C[lr][seg * 32];
      _Float16* dp = op + (size_t)grow * HID + seg * 32;
      #pragma unroll
      for (int q = 0; q < 4; ++q)
        *(uint4*)(dp + q * 8) = *(const uint4*)(sp + q * 8);
    }
  }
}

// ------------- layer GEMM: C[M][512] = A(f16)[M][256] @ WT^T ---------------
// BK=32, 2-buffer depth-1 prefetch with counted vmcnt(4), raw s_barrier
// pairs, lgkmcnt(0) guard before barrier2 (restage race, rule #18).
// 32KB LDS; (256,4) -> 128 VGPR cap, no spill (r10's (256,5) spilled).
__global__ __launch_bounds__(256, 4)
void k_gemm_h(const _Float16* __restrict__ A, int M,
              const _Float16* __restrict__ B,
              const float* __restrict__ bias0, const float* __restrict__ bias1,
              _Float16* __restrict__ outS, _Float16* __restrict__ outD)
{
  __shared__ __align__(16) char smem[32768];   // 2 bufs x (A 8K | B 8K)
  const int t = threadIdx.x, lane = t & 63, wid = t >> 6;
  const int wm = wid >> 1, wn = wid & 1;
  // XCD-chunked bijective swizzle (m204)
  const int nwg = gridDim.x, id = blockIdx.x;
  const int qc = nwg >> 3, rc = nwg & 7, xcd = id & 7, idx = id >> 3;
  const int swz = (xcd < rc ? xcd * (qc + 1) : rc * (qc + 1) + (xcd - rc) * qc) + idx;
  const int col0 = (swz & 3) * 128, row0 = (swz >> 2) * 128;

  f32x4 acc[4][4];
  #pragma unroll
  for (int i = 0; i < 4; ++i)
    #pragma unroll
    for (int j = 0; j < 4; ++j)
      acc[i][j] = (f32x4){0.f, 0.f, 0.f, 0.f};

  auto stage = [&](int kt, int buf) {
    const int kb = kt * 32;
    char* Ab = smem + buf * 16384;
    char* Bb = Ab + 8192;
    #pragma unroll
    for (int q = 0; q < 2; ++q) {
      int ci = wid * 2 + q;                  // 0..7, 1KB chunk = 16 rows
      int lr = lane >> 2;                    // local row 0..15
      int r = ci * 16 + lr;
      int slot = (lane & 3) ^ ((lr >> 1) & 3);
      int grow = row0 + r; grow = grow < M ? grow : (M - 1);
      gload16(A + (size_t)grow * HID + kb + slot * 8, Ab + ci * 1024);
      gload16(B + (size_t)(col0 + r) * HID + kb + slot * 8, Bb + ci * 1024);
    }
  };

  stage(0, 0);
  const int slot_off = (((lane >> 4) ^ ((lane >> 1) & 3)) << 4);
  const int ar0 = (wm * 64 + (lane & 15)) * 64 + slot_off;
  const int br0 = (wn * 64 + (lane & 15)) * 64 + slot_off;

  #pragma unroll
  for (int kt = 0; kt < 8; ++kt) {
    if (kt < 7) stage(kt + 1, (kt + 1) & 1);
    if (kt < 7) asm volatile("s_waitcnt vmcnt(4)" ::: "memory");
    else        asm volatile("s_waitcnt vmcnt(0)" ::: "memory");
    __builtin_amdgcn_s_barrier();
    __builtin_amdgcn_sched_barrier(0);
    const char* Ab = smem + (kt & 1) * 16384;
    const char* Bb = Ab + 8192;
    half8 af[4], bf[4];
    #pragma unroll
    for (int i = 0; i < 4; ++i) af[i] = *(const half8*)(Ab + ar0 + i * 1024);
    #pragma unroll
    for (int j = 0; j < 4; ++j) bf[j] = *(const half8*)(Bb + br0 + j * 1024);
    __builtin_amdgcn_s_setprio(1);
    #pragma unroll
    for (int i = 0; i < 4; ++i)
      #pragma unroll
      for (int j = 0; j < 4; ++j)
        acc[i][j] = __builtin_amdgcn_mfma_f32_16x16x32_f16(af[i], bf[j], acc[i][j], 0, 0, 0);
    __builtin_amdgcn_s_setprio(0);
    asm volatile("s_waitcnt lgkmcnt(0)" ::: "memory");
    __builtin_amdgcn_sched_barrier(0);
    __builtin_amdgcn_s_barrier();
    __builtin_amdgcn_sched_barrier(0);
  }
  gemm_epilogue2(acc, smem, t, lane, wm, wn, row0, col0, M, bias0, bias1, outS, outD);
}

// ------------- input GEMM: C[M][256] = atom(f32)[M][74] @ WTin^T -----------
__global__ __launch_bounds__(256)
void k_gemm_f(const float* __restrict__ A, int M,
              const _Float16* __restrict__ B,
              const float* __restrict__ bias0,
              _Float16* __restrict__ outS)
{
  __shared__ __align__(16) char smem[17408];
  const int t = threadIdx.x, lane = t & 63, wid = t >> 6;
  const int wm = wid >> 1, wn = wid & 1;
  const int nwg = gridDim.x, id = blockIdx.x;
  const int qc = nwg >> 3, rc = nwg & 7, xcd = id & 7, idx = id >> 3;
  const int swz = (xcd < rc ? xcd * (qc + 1) : rc * (qc + 1) + (xcd - rc) * qc) + idx;
  const int col0 = (swz & 1) * 128, row0 = (swz >> 1) * 128;
  char* Ab = smem;
  char* Bb = smem + 8192;

  f32x4 acc[4][4];
  #pragma unroll
  for (int i = 0; i < 4; ++i)
    #pragma unroll
    for (int j = 0; j < 4; ++j)
      acc[i][j] = (f32x4){0.f, 0.f, 0.f, 0.f};

  const int slot_off = (((lane >> 4) ^ ((lane >> 1) & 3)) << 4);
  const int ar0 = (wm * 64 + (lane & 15)) * 64 + slot_off;
  const int br0 = (wn * 64 + (lane & 15)) * 64 + slot_off;

  for (int kt = 0; kt < 3; ++kt) {
    const int kb = kt * 32;
    #pragma unroll
    for (int it = 0; it < 4; ++it) {
      int idx2 = t + it * 256;
      int r = idx2 >> 3, c4 = idx2 & 7;
      int gr = row0 + r;
      int k0 = kb + c4 * 4;
      float x0 = 0.f, x1 = 0.f, x2 = 0.f, x3 = 0.f;
      if (gr < M) {
        const float* ap = A + (size_t)gr * ADIM;
        if (k0 + 0 < ADIM) x0 = ap[k0 + 0];
        if (k0 + 1 < ADIM) x1 = ap[k0 + 1];
        if (k0 + 2 < ADIM) x2 = ap[k0 + 2];
        if (k0 + 3 < ADIM) x3 = ap[k0 + 3];
      }
      half4 hv = {(_Float16)x0, (_Float16)x1, (_Float16)x2, (_Float16)x3};
      int off = r * 64 + ((((c4 >> 1) ^ ((r >> 1) & 3)) << 4)) + (c4 & 1) * 8;
      *(half4*)(Ab + off) = hv;
    }
    #pragma unroll
    for (int q = 0; q < 2; ++q) {
      int ci = wid * 2 + q;
      int lr = lane >> 2;
      int r = ci * 16 + lr;
      int slot = (lane & 3) ^ ((lr >> 1) & 3);
      gload16(B + (size_t)(col0 + r) * KPAD_IN + kb + slot * 8, Bb + ci * 1024);
    }
    __syncthreads();
    half8 af[4], bf[4];
    #pragma unroll
    for (int i = 0; i < 4; ++i) af[i] = *(const half8*)(Ab + ar0 + i * 1024);
    #pragma unroll
    for (int j = 0; j < 4; ++j) bf[j] = *(const half8*)(Bb + br0 + j * 1024);
    #pragma unroll
    for (int i = 0; i < 4; ++i)
      #pragma unroll
      for (int j = 0; j < 4; ++j)
        acc[i][j] = __builtin_amdgcn_mfma_f32_16x16x32_f16(af[i], bf[j], acc[i][j], 0, 0, 0);
    __syncthreads();
  }
  gemm_epilogue2(acc, smem, t, lane, wm, wn, row0, col0, M, bias0, bias0, outS, outS);
}

// ------------- fused edge phase: online segment-softmax + aggregate --------
// TWO nodes per 32-lane group (perm[2g], perm[2g+1]; degree-sorted so the
// pair has equal degree). Both nodes' 2-edge-merged online-softmax chains
// run BRANCHLESS in one basic block -> 2x ILP on the serial shfl/exp chain
// and 2x gathers in flight. Per-edge validity: invalid -> logit -1e30 ->
// weight exactly 0, state untouched (degree-0 handled by inv=0).
__global__ __launch_bounds__(256)
void k_fused(const int* __restrict__ offs, const int* __restrict__ esrc,
             const int* __restrict__ perm,
             const _Float16* __restrict__ fs, const _Float16* __restrict__ fd,
             const float* __restrict__ attn, const float* __restrict__ bias,
             _Float16* __restrict__ hhalf, float* __restrict__ hfloat, int N)
{
  int grp = blockIdx.x * 8 + (threadIdx.x >> 5);
  int g0 = grp * 2;
  if (g0 >= N) return;
  const bool has1 = (g0 + 1) < N;
  int n0 = perm[g0];
  int n1 = has1 ? perm[g0 + 1] : n0;
  int sub = threadIdx.x & 31;
  int h = sub >> 3;
  int j0 = sub * 8;

  float4 av0 = *(const float4*)&attn[h * DOUT + (sub & 7) * 8];
  float4 av1 = *(const float4*)&attn[h * DOUT + (sub & 7) * 8 + 4];
  float4 bv0 = *(const float4*)&bias[j0];
  float4 bv1 = *(const float4*)&bias[j0 + 4];
  float avf[8] = {av0.x, av0.y, av0.z, av0.w, av1.x, av1.y, av1.z, av1.w};
  float bvf[8] = {bv0.x, bv0.y, bv0.z, bv0.w, bv1.x, bv1.y, bv1.z, bv1.w};

  half8 fdh0 = *(const half8*)&fd[(size_t)n0 * HID + j0];
  half8 fdh1 = *(const half8*)&fd[(size_t)n1 * HID + j0];
  float fd0[8], fd1[8];
  #pragma unroll
  for (int q = 0; q < 8; ++q) { fd0[q] = (float)fdh0[q]; fd1[q] = (float)fdh1[q]; }

  int t00 = offs[n0], t01 = offs[n0 + 1];
  int t10 = has1 ? offs[n1] : 0;
  int t11 = has1 ? offs[n1 + 1] : 0;

  float m0 = -1e30f, s0 = 0.f, m1 = -1e30f, s1 = 0.f;
  float a0[8], a1[8];
  #pragma unroll
  for (int q = 0; q < 8; ++q) { a0[q] = 0.f; a1[q] = 0.f; }

  // 2-deep prefetch per node
  half8 pA0 = {}, pB0 = {}, pA1 = {}, pB1 = {};
  if (t00 < t01)     pA0 = *(const half8*)&fs[(size_t)esrc[t00] * HID + j0];
  if (t00 + 1 < t01) pB0 = *(const half8*)&fs[(size_t)esrc[t00 + 1] * HID + j0];
  if (t10 < t11)     pA1 = *(const half8*)&fs[(size_t)esrc[t10] * HID + j0];
  if (t10 + 1 < t11) pB1 = *(const half8*)&fs[(size_t)esrc[t10 + 1] * HID + j0];

  int tt0 = t00, tt1 = t10;
  while (tt0 < t01 || tt1 < t11) {
    const bool vA0 = tt0 < t01, vB0 = tt0 + 1 < t01;
    const bool vA1 = tt1 < t11, vB1 = tt1 + 1 < t11;
    half8 fA0 = pA0, fB0 = pB0, fA1 = pA1, fB1 = pB1;
    pA0 = (half8){}; pB0 = (half8){}; pA1 = (half8){}; pB1 = (half8){};
    if (tt0 + 2 < t01) pA0 = *(const half8*)&fs[(size_t)esrc[tt0 + 2] * HID + j0];
    if (tt0 + 3 < t01) pB0 = *(const half8*)&fs[(size_t)esrc[tt0 + 3] * HID + j0];
    if (tt1 + 2 < t11) pA1 = *(const half8*)&fs[(size_t)esrc[tt1 + 2] * HID + j0];
    if (tt1 + 3 < t11) pB1 = *(const half8*)&fs[(size_t)esrc[tt1 + 3] * HID + j0];

    float fa0[8], fb0[8], fa1[8], fb1[8];
    #pragma unroll
    for (int q = 0; q < 8; ++q) {
      fa0[q] = (float)fA0[q]; fb0[q] = (float)fB0[q];
      fa1[q] = (float)fA1[q]; fb1[q] = (float)fB1[q];
    }
    float qa0 = 0.f, qb0 = 0.f, qa1 = 0.f, qb1 = 0.f;
    #pragma unroll
    for (int q = 0; q < 8; ++q) {
      float x;
      x = fa0[q] + fd0[q]; x = x > 0.f ? x : 0.2f * x; qa0 += x * avf[q];
      x = fb0[q] + fd0[q]; x = x > 0.f ? x : 0.2f * x; qb0 += x * avf[q];
      x = fa1[q] + fd1[q]; x = x > 0.f ? x : 0.2f * x; qa1 += x * avf[q];
      x = fb1[q] + fd1[q]; x = x > 0.f ? x : 0.2f * x; qb1 += x * avf[q];
    }
    qa0 += __shfl_xor(qa0, 1); qb0 += __shfl_xor(qb0, 1);
    qa1 += __shfl_xor(qa1, 1); qb1 += __shfl_xor(qb1, 1);
    qa0 += __shfl_xor(qa0, 2); qb0 += __shfl_xor(qb0, 2);
    qa1 += __shfl_xor(qa1, 2); qb1 += __shfl_xor(qb1, 2);
    qa0 += __shfl_xor(qa0, 4); qb0 += __shfl_xor(qb0, 4);
    qa1 += __shfl_xor(qa1, 4); qb1 += __shfl_xor(qb1, 4);
    qa0 = vA0 ? qa0 : -1e30f;
    qb0 = vB0 ? qb0 : -1e30f;
    qa1 = vA1 ? qa1 : -1e30f;
    qb1 = vB1 ? qb1 : -1e30f;
    // node0 merge
    float mx0 = fmaxf(fmaxf(qa0, qb0), m0);
    float sc0 = __expf(m0 - mx0);
    float wa0 = __expf(qa0 - mx0);
    float wb0 = __expf(qb0 - mx0);
    // node1 merge
    float mx1 = fmaxf(fmaxf(qa1, qb1), m1);
    float sc1 = __expf(m1 - mx1);
    float wa1 = __expf(qa1 - mx1);
    float wb1 = __expf(qb1 - mx1);
    s0 = s0 * sc0 + wa0 + wb0;
    s1 = s1 * sc1 + wa1 + wb1;
    #pragma unroll
    for (int q = 0; q < 8; ++q) {
      a0[q] = a0[q] * sc0 + wa0 * fa0[q] + wb0 * fb0[q];
      a1[q] = a1[q] * sc1 + wa1 * fa1[q] + wb1 * fb1[q];
    }
    m0 = mx0; m1 = mx1;
    tt0 += 2; tt1 += 2;
  }

  float inv0 = (t01 > t00) ? 1.0f / s0 : 0.f;
  float o0[8];
  #pragma unroll
  for (int q = 0; q < 8; ++q) o0[q] = a0[q] * inv0 + bvf[q];
  if (hhalf) {
    half8 hv;
    #pragma unroll
    for (int q = 0; q < 8; ++q) hv[q] = (_Float16)o0[q];
    *(half8*)&hhalf[(size_t)n0 * HID + j0] = hv;
  }
  if (hfloat) {
    float4 v0 = {o0[0], o0[1], o0[2], o0[3]};
    float4 v1 = {o0[4], o0[5], o0[6], o0[7]};
    *(float4*)&hfloat[(size_t)n0 * HID + j0] = v0;
    *(float4*)&hfloat[(size_t)n0 * HID + j0 + 4] = v1;
  }
  if (has1) {
    float inv1 = (t11 > t10) ? 1.0f / s1 : 0.f;
    float o1[8];
    #pragma unroll
    for (int q = 0; q < 8; ++q) o1[q] = a1[q] * inv1 + bvf[q];
    if (hhalf) {
      half8 hv;
      #pragma unroll
      for (int q = 0; q < 8; ++q) hv[q] = (_Float16)o1[q];
      *(half8*)&hhalf[(size_t)n1 * HID + j0] = hv;
    }
    if (hfloat) {
      float4 v0 = {o1[0], o1[1], o1[2], o1[3]};
      float4 v1 = {o1[4], o1[5], o1[6], o1[7]};
      *(float4*)&hfloat[(size_t)n1 * HID + j0] = v0;
      *(float4*)&hfloat[(size_t)n1 * HID + j0 + 4] = v1;
    }
  }
}

// ---------------- CSR build + degree sort ----------------------------------
__global__ void k_count(const int* __restrict__ dst, int* __restrict__ counts, int E) {
  int i = blockIdx.x * 256 + threadIdx.x;
  if (i < E) atomicAdd(&counts[dst[i]], 1);
}
__global__ __launch_bounds__(1024)
void k_scan1(const int* __restrict__ counts, int* __restrict__ offs,
             int* __restrict__ bsums, int* __restrict__ dhist, int N)
{
  __shared__ int sd[1024];
  __shared__ int hh[64];
  int t = threadIdx.x, i = blockIdx.x * 1024 + t;
  if (t < 64) hh[t] = 0;
  int x = (i < N) ? counts[i] : 0;
  sd[t] = x;
  __syncthreads();
  if (i < N) atomicAdd(&hh[x < 63 ? x : 63], 1);
  for (int off = 1; off < 1024; off <<= 1) {
    int v = (t >= off) ? sd[t - off] : 0;
    __syncthreads();
    sd[t] += v;
    __syncthreads();
  }
  if (i < N) offs[i] = sd[t] - x;
  if (t == 0) bsums[blockIdx.x] = sd[1023];
  __syncthreads();
  if (t < 64 && hh[t] > 0) atomicAdd(&dhist[t], hh[t]);
}
// block scan-carry + degree-bin prefix in one tiny launch
__global__ void k_scan2(const int* __restrict__ bsums, int* __restrict__ boffs,
                        int* __restrict__ offs, int nb, int N,
                        const int* __restrict__ dhist, int* __restrict__ dcur)
{
  int t = threadIdx.x;           // 64 threads
  int x = dhist[t];
  int sum = x;
  for (int off = 1; off < 64; off <<= 1) {
    int v = __shfl_up(sum, off);
    if (t >= off) sum += v;
  }
  dcur[t] = sum - x;
  if (t == 0) {
    int run = 0;
    for (int b = 0; b < nb; ++b) { boffs[b] = run; run += bsums[b]; }
    offs[N] = run;
  }
}
__global__ __launch_bounds__(1024)
void k_scan3(const int* __restrict__ boffs, int* __restrict__ offs,
             int* __restrict__ cursor, int N)
{
  int i = blockIdx.x * 1024 + threadIdx.x;
  if (i < N) {
    int v = offs[i] + boffs[blockIdx.x];
    offs[i] = v;
    cursor[i] = v;
  }
}
__global__ void k_scatter(const int* __restrict__ src, const int* __restrict__ dst,
                          int* __restrict__ cursor, int* __restrict__ esrc, int E)
{
  int i = blockIdx.x * 256 + threadIdx.x;
  if (i < E) {
    int pos = atomicAdd(&cursor[dst[i]], 1);
    esrc[pos] = src[i];
  }
}
__global__ __launch_bounds__(256)
void k_deg_scatter(const int* __restrict__ counts, int* __restrict__ dcur,
                   int* __restrict__ perm, int N)
{
  __shared__ int hist[64];
  __shared__ int base[64];
  int t = threadIdx.x;
  int i = blockIdx.x * 256 + t;
  if (t < 64) hist[t] = 0;
  __syncthreads();
  int d = 0, lrank = 0;
  if (i < N) {
    d = counts[i]; d = d < 63 ? d : 63;
    lrank = atomicAdd(&hist[d], 1);
  }
  __syncthreads();
  if (t < 64 && hist[t] > 0) base[t] = atomicAdd(&dcur[t], hist[t]);
  __syncthreads();
  if (i < N) perm[base[d] + lrank] = i;
}

// ---------------- launch ---------------------------------------------------
extern "C" void kernel_launch(void* const* d_in, const int* in_sizes, int n_in,
                              void* d_out, int out_size, void* d_ws, size_t ws_size,
                              hipStream_t stream)
{
  const float* atom  = (const float*)d_in[0];
  const int*   src   = (const int*)d_in[1];
  const int*   dst   = (const int*)d_in[2];
  const float* W_in  = (const float*)d_in[3];
  const float* b_in  = (const float*)d_in[4];
  const float* W_src = (const float*)d_in[5];
  const float* b_src = (const float*)d_in[6];
  const float* W_dst = (const float*)d_in[7];
  const float* b_dst = (const float*)d_in[8];
  const float* attn  = (const float*)d_in[9];
  const float* bias  = (const float*)d_in[10];

  const int N = in_sizes[0] / ADIM;
  const int E = in_sizes[1];
  _Float16* h_half = (_Float16*)d_out;
  float*    h_out  = (float*)d_out;

  char* w = (char*)d_ws;
  size_t off = 0;
  auto carve = [&](size_t bytes) {
    void* p = w + off;
    off = (off + bytes + 255) & ~(size_t)255;
    return p;
  };
  _Float16* fs    = (_Float16*)carve((size_t)N * HID * 2);
  _Float16* fd    = (_Float16*)carve((size_t)N * HID * 2);
  _Float16* WT    = (_Float16*)carve((size_t)LAYERS * 512 * HID * 2);
  _Float16* WTin  = (_Float16*)carve((size_t)HID * KPAD_IN * 2);
  int*      counts= (int*)carve((size_t)(N + 64) * 4);   // counts[N] + dhist[64]
  int*      offs  = (int*)carve((size_t)(N + 1) * 4);
  int*      cursor= (int*)carve((size_t)N * 4);
  int*      esrc  = (int*)carve((size_t)E * 4);
  int*      perm  = (int*)carve((size_t)N * 4);
  int*      dcur  = (int*)carve((size_t)64 * 4);
  int*      bsums = (int*)carve((size_t)1024 * 4);
  int*      boffs = (int*)carve((size_t)1024 * 4);
  int*      dhist = counts + N;
  (void)ws_size; (void)n_in; (void)out_size;

  const int nb = (N + 1023) / 1024;
  const int gmx = (N + 127) / 128;

  // CSR by dst + degree sort (layer-invariant)
  hipMemsetAsync(counts, 0, (size_t)(N + 64) * 4, stream);
  k_count<<<(E + 255) / 256, 256, 0, stream>>>(dst, counts, E);
  k_scan1<<<nb, 1024, 0, stream>>>(counts, offs, bsums, dhist, N);
  k_scan2<<<1, 64, 0, stream>>>(bsums, boffs, offs, nb, N, dhist, dcur);
  k_scan3<<<nb, 1024, 0, stream>>>(boffs, offs, cursor, N);
  k_scatter<<<(E + 255) / 256, 256, 0, stream>>>(src, dst, cursor, esrc, E);
  k_deg_scatter<<<(N + 255) / 256, 256, 0, stream>>>(counts, dcur, perm, N);

  // weight prep (all layers + input) + input projection
  k_prep<<<dim3(512, LAYERS + 1), 256, 0, stream>>>(W_src, W_dst, W_in, WT, WTin);
  k_gemm_f<<<2 * gmx, 256, 0, stream>>>(atom, N, WTin, b_in, h_half);

  for (int l = 0; l < LAYERS; ++l) {
    k_gemm_h<<<4 * gmx, 256, 0, stream>>>(h_half, N, WT + (size_t)l * 512 * HID,
                                          b_src + (size_t)l * HID,
                                          b_dst + (size_t)l * HID, fs, fd);
    const bool last = (l == LAYERS - 1);
    k_fused<<<(N + 15) / 16, 256, 0, stream>>>(offs, esrc, perm, fs, fd,
                                               attn + (size_t)l * NHEAD * DOUT,
                                               bias + (size_t)l * HID,
                                               last ? nullptr : h_half,
                                               last ? h_out : nullptr, N);
  }
}

// Round 15
// 430.955 us; speedup vs baseline: 1.0935x; 1.0935x over previous
//
#include <hip/hip_runtime.h>
#include <hip/hip_fp16.h>

#define HID   256
#define NHEAD 4
#define DOUT  64
#define ADIM  74
#define KPAD_IN 96
#define LAYERS 3

typedef _Float16 half8 __attribute__((ext_vector_type(8)));
typedef _Float16 half4 __attribute__((ext_vector_type(4)));
typedef _Float16 half2v __attribute__((ext_vector_type(2)));
typedef float f32x4 __attribute__((ext_vector_type(4)));

__device__ __forceinline__ void gload16(const void* g, void* l) {
  __builtin_amdgcn_global_load_lds((const __attribute__((address_space(1))) void*)g,
                                   (__attribute__((address_space(3))) void*)l, 16, 0, 0);
}

// -------- weight prep (all layers + input proj in one launch) --------------
__global__ void k_prep(const float* __restrict__ Ws, const float* __restrict__ Wd,
                       const float* __restrict__ Win,
                       _Float16* __restrict__ WT, _Float16* __restrict__ WTin) {
  int l = blockIdx.y;
  int id = blockIdx.x * 256 + threadIdx.x;
  if (l < LAYERS) {
    if (id >= 512 * HID) return;
    int n = id >> 8, k = id & 255;
    const float* W = (n < HID) ? (Ws + (size_t)l * HID * HID)
                               : (Wd + (size_t)l * HID * HID);
    int nn = (n < HID) ? n : (n - HID);
    WT[(size_t)l * 512 * HID + id] = (_Float16)W[k * HID + nn];
  } else {
    if (id >= HID * KPAD_IN) return;
    int n = id / KPAD_IN, k = id % KPAD_IN;
    WTin[id] = (_Float16)((k < ADIM) ? Win[k * HID + n] : 0.f);
  }
}

// ---- 2-pass epilogue: acc -> LDS f16 [64][136] -> coalesced 64B stores ----
__device__ __forceinline__ void gemm_epilogue2(
    f32x4 acc[4][4], char* smem, int t, int lane, int wm, int wn,
    int row0, int col0, int M,
    const float* bias0, const float* bias1,
    _Float16* outS, _Float16* outD)
{
  const float* bp = (col0 < HID) ? (bias0 + col0) : (bias1 + (col0 - HID));
  _Float16*    op = (col0 < HID) ? (outS + col0) : (outD + (col0 - HID));
  _Float16 (*C)[136] = (_Float16(*)[136])smem;   // 64 x 136 x 2B = 17408 B
  #pragma unroll
  for (int half = 0; half < 2; ++half) {
    __syncthreads();
    if (wm == half) {
      #pragma unroll
      for (int i = 0; i < 4; ++i) {
        #pragma unroll
        for (int j = 0; j < 4; ++j) {
          int lc = wn * 64 + j * 16 + (lane & 15);
          float bv = bp[lc];
          #pragma unroll
          for (int r = 0; r < 4; ++r) {
            int lr = i * 16 + (lane >> 4) * 4 + r;
            C[lr][lc] = (_Float16)(acc[i][j][r] + bv);
          }
        }
      }
    }
    __syncthreads();
    int lr = t >> 2, seg = t & 3;
    int grow = row0 + half * 64 + lr;
    if (grow < M) {
      const _Float16* sp = &C[lr][seg * 32];
      _Float16* dp = op + (size_t)grow * HID + seg * 32;
      #pragma unroll
      for (int q = 0; q < 4; ++q)
        *(uint4*)(dp + q * 8) = *(const uint4*)(sp + q * 8);
    }
  }
}

// ------------- layer GEMM: C[M][512] = A(f16)[M][256] @ WT^T ---------------
// BK=32, 2-buffer depth-1 prefetch with counted vmcnt(4), raw s_barrier
// pairs, lgkmcnt(0) guard before barrier2 (restage race, rule #18).
// 32KB LDS; (256,4) -> 128 VGPR cap, no spill (r10's (256,5) spilled).
__global__ __launch_bounds__(256, 4)
void k_gemm_h(const _Float16* __restrict__ A, int M,
              const _Float16* __restrict__ B,
              const float* __restrict__ bias0, const float* __restrict__ bias1,
              _Float16* __restrict__ outS, _Float16* __restrict__ outD)
{
  __shared__ __align__(16) char smem[32768];   // 2 bufs x (A 8K | B 8K)
  const int t = threadIdx.x, lane = t & 63, wid = t >> 6;
  const int wm = wid >> 1, wn = wid & 1;
  // XCD-chunked bijective swizzle (m204)
  const int nwg = gridDim.x, id = blockIdx.x;
  const int qc = nwg >> 3, rc = nwg & 7, xcd = id & 7, idx = id >> 3;
  const int swz = (xcd < rc ? xcd * (qc + 1) : rc * (qc + 1) + (xcd - rc) * qc) + idx;
  const int col0 = (swz & 3) * 128, row0 = (swz >> 2) * 128;

  f32x4 acc[4][4];
  #pragma unroll
  for (int i = 0; i < 4; ++i)
    #pragma unroll
    for (int j = 0; j < 4; ++j)
      acc[i][j] = (f32x4){0.f, 0.f, 0.f, 0.f};

  auto stage = [&](int kt, int buf) {
    const int kb = kt * 32;
    char* Ab = smem + buf * 16384;
    char* Bb = Ab + 8192;
    #pragma unroll
    for (int q = 0; q < 2; ++q) {
      int ci = wid * 2 + q;                  // 0..7, 1KB chunk = 16 rows
      int lr = lane >> 2;                    // local row 0..15
      int r = ci * 16 + lr;
      int slot = (lane & 3) ^ ((lr >> 1) & 3);
      int grow = row0 + r; grow = grow < M ? grow : (M - 1);
      gload16(A + (size_t)grow * HID + kb + slot * 8, Ab + ci * 1024);
      gload16(B + (size_t)(col0 + r) * HID + kb + slot * 8, Bb + ci * 1024);
    }
  };

  stage(0, 0);
  const int slot_off = (((lane >> 4) ^ ((lane >> 1) & 3)) << 4);
  const int ar0 = (wm * 64 + (lane & 15)) * 64 + slot_off;
  const int br0 = (wn * 64 + (lane & 15)) * 64 + slot_off;

  #pragma unroll
  for (int kt = 0; kt < 8; ++kt) {
    if (kt < 7) stage(kt + 1, (kt + 1) & 1);
    if (kt < 7) asm volatile("s_waitcnt vmcnt(4)" ::: "memory");
    else        asm volatile("s_waitcnt vmcnt(0)" ::: "memory");
    __builtin_amdgcn_s_barrier();
    __builtin_amdgcn_sched_barrier(0);
    const char* Ab = smem + (kt & 1) * 16384;
    const char* Bb = Ab + 8192;
    half8 af[4], bf[4];
    #pragma unroll
    for (int i = 0; i < 4; ++i) af[i] = *(const half8*)(Ab + ar0 + i * 1024);
    #pragma unroll
    for (int j = 0; j < 4; ++j) bf[j] = *(const half8*)(Bb + br0 + j * 1024);
    __builtin_amdgcn_s_setprio(1);
    #pragma unroll
    for (int i = 0; i < 4; ++i)
      #pragma unroll
      for (int j = 0; j < 4; ++j)
        acc[i][j] = __builtin_amdgcn_mfma_f32_16x16x32_f16(af[i], bf[j], acc[i][j], 0, 0, 0);
    __builtin_amdgcn_s_setprio(0);
    asm volatile("s_waitcnt lgkmcnt(0)" ::: "memory");
    __builtin_amdgcn_sched_barrier(0);
    __builtin_amdgcn_s_barrier();
    __builtin_amdgcn_sched_barrier(0);
  }
  gemm_epilogue2(acc, smem, t, lane, wm, wn, row0, col0, M, bias0, bias1, outS, outD);
}

// ------------- input GEMM: C[M][256] = atom(f32)[M][74] @ WTin^T -----------
__global__ __launch_bounds__(256)
void k_gemm_f(const float* __restrict__ A, int M,
              const _Float16* __restrict__ B,
              const float* __restrict__ bias0,
              _Float16* __restrict__ outS)
{
  __shared__ __align__(16) char smem[17408];
  const int t = threadIdx.x, lane = t & 63, wid = t >> 6;
  const int wm = wid >> 1, wn = wid & 1;
  const int nwg = gridDim.x, id = blockIdx.x;
  const int qc = nwg >> 3, rc = nwg & 7, xcd = id & 7, idx = id >> 3;
  const int swz = (xcd < rc ? xcd * (qc + 1) : rc * (qc + 1) + (xcd - rc) * qc) + idx;
  const int col0 = (swz & 1) * 128, row0 = (swz >> 1) * 128;
  char* Ab = smem;
  char* Bb = smem + 8192;

  f32x4 acc[4][4];
  #pragma unroll
  for (int i = 0; i < 4; ++i)
    #pragma unroll
    for (int j = 0; j < 4; ++j)
      acc[i][j] = (f32x4){0.f, 0.f, 0.f, 0.f};

  const int slot_off = (((lane >> 4) ^ ((lane >> 1) & 3)) << 4);
  const int ar0 = (wm * 64 + (lane & 15)) * 64 + slot_off;
  const int br0 = (wn * 64 + (lane & 15)) * 64 + slot_off;

  for (int kt = 0; kt < 3; ++kt) {
    const int kb = kt * 32;
    #pragma unroll
    for (int it = 0; it < 4; ++it) {
      int idx2 = t + it * 256;
      int r = idx2 >> 3, c4 = idx2 & 7;
      int gr = row0 + r;
      int k0 = kb + c4 * 4;
      float x0 = 0.f, x1 = 0.f, x2 = 0.f, x3 = 0.f;
      if (gr < M) {
        const float* ap = A + (size_t)gr * ADIM;
        if (k0 + 0 < ADIM) x0 = ap[k0 + 0];
        if (k0 + 1 < ADIM) x1 = ap[k0 + 1];
        if (k0 + 2 < ADIM) x2 = ap[k0 + 2];
        if (k0 + 3 < ADIM) x3 = ap[k0 + 3];
      }
      half4 hv = {(_Float16)x0, (_Float16)x1, (_Float16)x2, (_Float16)x3};
      int off = r * 64 + ((((c4 >> 1) ^ ((r >> 1) & 3)) << 4)) + (c4 & 1) * 8;
      *(half4*)(Ab + off) = hv;
    }
    #pragma unroll
    for (int q = 0; q < 2; ++q) {
      int ci = wid * 2 + q;
      int lr = lane >> 2;
      int r = ci * 16 + lr;
      int slot = (lane & 3) ^ ((lr >> 1) & 3);
      gload16(B + (size_t)(col0 + r) * KPAD_IN + kb + slot * 8, Bb + ci * 1024);
    }
    __syncthreads();
    half8 af[4], bf[4];
    #pragma unroll
    for (int i = 0; i < 4; ++i) af[i] = *(const half8*)(Ab + ar0 + i * 1024);
    #pragma unroll
    for (int j = 0; j < 4; ++j) bf[j] = *(const half8*)(Bb + br0 + j * 1024);
    #pragma unroll
    for (int i = 0; i < 4; ++i)
      #pragma unroll
      for (int j = 0; j < 4; ++j)
        acc[i][j] = __builtin_amdgcn_mfma_f32_16x16x32_f16(af[i], bf[j], acc[i][j], 0, 0, 0);
    __syncthreads();
  }
  gemm_epilogue2(acc, smem, t, lane, wm, wn, row0, col0, M, bias0, bias0, outS, outS);
}

// ------------- fused edge phase: online segment-softmax + aggregate --------
// r11 structure (1 node per 32-lane group, 2-edge merge, depth-2 prefetch)
// + ISOLATED change: packed-f16 logit path. pk_add/pk_mul/pk_max directly
// on the loaded half8 bits (reinterpret as 4x half2, no repack) + fdot2
// with f32 accumulate. Aggregation stays f32 (cvt retained).
__global__ __launch_bounds__(256)
void k_fused(const int* __restrict__ offs, const int* __restrict__ esrc,
             const int* __restrict__ perm,
             const _Float16* __restrict__ fs, const _Float16* __restrict__ fd,
             const float* __restrict__ attn, const float* __restrict__ bias,
             _Float16* __restrict__ hhalf, float* __restrict__ hfloat, int N)
{
  int gid = blockIdx.x * 8 + (threadIdx.x >> 5);
  if (gid >= N) return;
  int n = perm[gid];
  int sub = threadIdx.x & 31;
  int h = sub >> 3;
  int j0 = sub * 8;
  half8 fdv = *(const half8*)&fd[(size_t)n * HID + j0];
  const half2v* fd2 = (const half2v*)&fdv;
  float4 av0 = *(const float4*)&attn[h * DOUT + (sub & 7) * 8];
  float4 av1 = *(const float4*)&attn[h * DOUT + (sub & 7) * 8 + 4];
  float4 bv0 = *(const float4*)&bias[j0];
  float4 bv1 = *(const float4*)&bias[j0 + 4];
  half2v avh[4];
  avh[0] = (half2v){(_Float16)av0.x, (_Float16)av0.y};
  avh[1] = (half2v){(_Float16)av0.z, (_Float16)av0.w};
  avh[2] = (half2v){(_Float16)av1.x, (_Float16)av1.y};
  avh[3] = (half2v){(_Float16)av1.z, (_Float16)av1.w};
  const half2v c02 = {(_Float16)0.2f, (_Float16)0.2f};
  float bvf[8] = {bv0.x, bv0.y, bv0.z, bv0.w, bv1.x, bv1.y, bv1.z, bv1.w};

  int t0 = offs[n], t1 = offs[n + 1];
  float m = -1e30f, ssum = 0.f;
  float a[8];
  #pragma unroll
  for (int q = 0; q < 8; ++q) a[q] = 0.f;

  half8 fA = {}, fB = {};
  if (t0 < t1)     fA = *(const half8*)&fs[(size_t)esrc[t0] * HID + j0];
  if (t0 + 1 < t1) fB = *(const half8*)&fs[(size_t)esrc[t0 + 1] * HID + j0];
  int tt = t0;
  for (; tt + 1 < t1; tt += 2) {
    half8 fcA = fA, fcB = fB;
    if (tt + 2 < t1) fA = *(const half8*)&fs[(size_t)esrc[tt + 2] * HID + j0];
    if (tt + 3 < t1) fB = *(const half8*)&fs[(size_t)esrc[tt + 3] * HID + j0];
    // packed-f16 logit dots (f32 accumulate via v_dot2_f32_f16)
    const half2v* pa2 = (const half2v*)&fcA;
    const half2v* pb2 = (const half2v*)&fcB;
    float pa = 0.f, pb = 0.f;
    #pragma unroll
    for (int q = 0; q < 4; ++q) {
      half2v xa = pa2[q] + fd2[q];
      half2v xb = pb2[q] + fd2[q];
      half2v la = __builtin_elementwise_max(xa, xa * c02);
      half2v lb = __builtin_elementwise_max(xb, xb * c02);
      pa = __builtin_amdgcn_fdot2(la, avh[q], pa, false);
      pb = __builtin_amdgcn_fdot2(lb, avh[q], pb, false);
    }
    pa += __shfl_xor(pa, 1); pb += __shfl_xor(pb, 1);
    pa += __shfl_xor(pa, 2); pb += __shfl_xor(pb, 2);
    pa += __shfl_xor(pa, 4); pb += __shfl_xor(pb, 4);
    float mx = fmaxf(m, fmaxf(pa, pb));
    float sc = __expf(m - mx);
    float wa = __expf(pa - mx);
    float wb = __expf(pb - mx);
    ssum = ssum * sc + wa + wb;
    float fa[8], fb[8];
    #pragma unroll
    for (int q = 0; q < 8; ++q) { fa[q] = (float)fcA[q]; fb[q] = (float)fcB[q]; }
    #pragma unroll
    for (int q = 0; q < 8; ++q) a[q] = a[q] * sc + wa * fa[q] + wb * fb[q];
    m = mx;
  }
  if (tt < t1) {   // odd tail edge (its row sits in fA)
    const half2v* pa2 = (const half2v*)&fA;
    float pa = 0.f;
    #pragma unroll
    for (int q = 0; q < 4; ++q) {
      half2v xa = pa2[q] + fd2[q];
      half2v la = __builtin_elementwise_max(xa, xa * c02);
      pa = __builtin_amdgcn_fdot2(la, avh[q], pa, false);
    }
    pa += __shfl_xor(pa, 1);
    pa += __shfl_xor(pa, 2);
    pa += __shfl_xor(pa, 4);
    float mx = fmaxf(m, pa);
    float sc = __expf(m - mx);
    float wa = __expf(pa - mx);
    ssum = ssum * sc + wa;
    #pragma unroll
    for (int q = 0; q < 8; ++q) a[q] = a[q] * sc + wa * (float)fA[q];
    m = mx;
  }
  float inv = (t1 > t0) ? 1.0f / ssum : 0.f;
  float o[8];
  #pragma unroll
  for (int q = 0; q < 8; ++q) o[q] = a[q] * inv + bvf[q];
  if (hhalf) {
    half8 hv;
    #pragma unroll
    for (int q = 0; q < 8; ++q) hv[q] = (_Float16)o[q];
    *(half8*)&hhalf[(size_t)n * HID + j0] = hv;
  }
  if (hfloat) {
    float4 v0 = {o[0], o[1], o[2], o[3]};
    float4 v1 = {o[4], o[5], o[6], o[7]};
    *(float4*)&hfloat[(size_t)n * HID + j0] = v0;
    *(float4*)&hfloat[(size_t)n * HID + j0 + 4] = v1;
  }
}

// ---------------- CSR build + degree sort ----------------------------------
__global__ void k_count(const int* __restrict__ dst, int* __restrict__ counts, int E) {
  int i = blockIdx.x * 256 + threadIdx.x;
  if (i < E) atomicAdd(&counts[dst[i]], 1);
}
__global__ __launch_bounds__(1024)
void k_scan1(const int* __restrict__ counts, int* __restrict__ offs,
             int* __restrict__ bsums, int* __restrict__ dhist, int N)
{
  __shared__ int sd[1024];
  __shared__ int hh[64];
  int t = threadIdx.x, i = blockIdx.x * 1024 + t;
  if (t < 64) hh[t] = 0;
  int x = (i < N) ? counts[i] : 0;
  sd[t] = x;
  __syncthreads();
  if (i < N) atomicAdd(&hh[x < 63 ? x : 63], 1);
  for (int off = 1; off < 1024; off <<= 1) {
    int v = (t >= off) ? sd[t - off] : 0;
    __syncthreads();
    sd[t] += v;
    __syncthreads();
  }
  if (i < N) offs[i] = sd[t] - x;
  if (t == 0) bsums[blockIdx.x] = sd[1023];
  __syncthreads();
  if (t < 64 && hh[t] > 0) atomicAdd(&dhist[t], hh[t]);
}
// block scan-carry + degree-bin prefix in one tiny launch
__global__ void k_scan2(const int* __restrict__ bsums, int* __restrict__ boffs,
                        int* __restrict__ offs, int nb, int N,
                        const int* __restrict__ dhist, int* __restrict__ dcur)
{
  int t = threadIdx.x;           // 64 threads
  int x = dhist[t];
  int sum = x;
  for (int off = 1; off < 64; off <<= 1) {
    int v = __shfl_up(sum, off);
    if (t >= off) sum += v;
  }
  dcur[t] = sum - x;
  if (t == 0) {
    int run = 0;
    for (int b = 0; b < nb; ++b) { boffs[b] = run; run += bsums[b]; }
    offs[N] = run;
  }
}
__global__ __launch_bounds__(1024)
void k_scan3(const int* __restrict__ boffs, int* __restrict__ offs,
             int* __restrict__ cursor, int N)
{
  int i = blockIdx.x * 1024 + threadIdx.x;
  if (i < N) {
    int v = offs[i] + boffs[blockIdx.x];
    offs[i] = v;
    cursor[i] = v;
  }
}
__global__ void k_scatter(const int* __restrict__ src, const int* __restrict__ dst,
                          int* __restrict__ cursor, int* __restrict__ esrc, int E)
{
  int i = blockIdx.x * 256 + threadIdx.x;
  if (i < E) {
    int pos = atomicAdd(&cursor[dst[i]], 1);
    esrc[pos] = src[i];
  }
}
__global__ __launch_bounds__(256)
void k_deg_scatter(const int* __restrict__ counts, int* __restrict__ dcur,
                   int* __restrict__ perm, int N)
{
  __shared__ int hist[64];
  __shared__ int base[64];
  int t = threadIdx.x;
  int i = blockIdx.x * 256 + t;
  if (t < 64) hist[t] = 0;
  __syncthreads();
  int d = 0, lrank = 0;
  if (i < N) {
    d = counts[i]; d = d < 63 ? d : 63;
    lrank = atomicAdd(&hist[d], 1);
  }
  __syncthreads();
  if (t < 64 && hist[t] > 0) base[t] = atomicAdd(&dcur[t], hist[t]);
  __syncthreads();
  if (i < N) perm[base[d] + lrank] = i;
}

// ---------------- launch ---------------------------------------------------
extern "C" void kernel_launch(void* const* d_in, const int* in_sizes, int n_in,
                              void* d_out, int out_size, void* d_ws, size_t ws_size,
                              hipStream_t stream)
{
  const float* atom  = (const float*)d_in[0];
  const int*   src   = (const int*)d_in[1];
  const int*   dst   = (const int*)d_in[2];
  const float* W_in  = (const float*)d_in[3];
  const float* b_in  = (const float*)d_in[4];
  const float* W_src = (const float*)d_in[5];
  const float* b_src = (const float*)d_in[6];
  const float* W_dst = (const float*)d_in[7];
  const float* b_dst = (const float*)d_in[8];
  const float* attn  = (const float*)d_in[9];
  const float* bias  = (const float*)d_in[10];

  const int N = in_sizes[0] / ADIM;
  const int E = in_sizes[1];
  _Float16* h_half = (_Float16*)d_out;
  float*    h_out  = (float*)d_out;

  char* w = (char*)d_ws;
  size_t off = 0;
  auto carve = [&](size_t bytes) {
    void* p = w + off;
    off = (off + bytes + 255) & ~(size_t)255;
    return p;
  };
  _Float16* fs    = (_Float16*)carve((size_t)N * HID * 2);
  _Float16* fd    = (_Float16*)carve((size_t)N * HID * 2);
  _Float16* WT    = (_Float16*)carve((size_t)LAYERS * 512 * HID * 2);
  _Float16* WTin  = (_Float16*)carve((size_t)HID * KPAD_IN * 2);
  int*      counts= (int*)carve((size_t)(N + 64) * 4);   // counts[N] + dhist[64]
  int*      offs  = (int*)carve((size_t)(N + 1) * 4);
  int*      cursor= (int*)carve((size_t)N * 4);
  int*      esrc  = (int*)carve((size_t)E * 4);
  int*      perm  = (int*)carve((size_t)N * 4);
  int*      dcur  = (int*)carve((size_t)64 * 4);
  int*      bsums = (int*)carve((size_t)1024 * 4);
  int*      boffs = (int*)carve((size_t)1024 * 4);
  int*      dhist = counts + N;
  (void)ws_size; (void)n_in; (void)out_size;

  const int nb = (N + 1023) / 1024;
  const int gmx = (N + 127) / 128;

  // CSR by dst + degree sort (layer-invariant)
  hipMemsetAsync(counts, 0, (size_t)(N + 64) * 4, stream);
  k_count<<<(E + 255) / 256, 256, 0, stream>>>(dst, counts, E);
  k_scan1<<<nb, 1024, 0, stream>>>(counts, offs, bsums, dhist, N);
  k_scan2<<<1, 64, 0, stream>>>(bsums, boffs, offs, nb, N, dhist, dcur);
  k_scan3<<<nb, 1024, 0, stream>>>(boffs, offs, cursor, N);
  k_scatter<<<(E + 255) / 256, 256, 0, stream>>>(src, dst, cursor, esrc, E);
  k_deg_scatter<<<(N + 255) / 256, 256, 0, stream>>>(counts, dcur, perm, N);

  // weight prep (all layers + input) + input projection
  k_prep<<<dim3(512, LAYERS + 1), 256, 0, stream>>>(W_src, W_dst, W_in, WT, WTin);
  k_gemm_f<<<2 * gmx, 256, 0, stream>>>(atom, N, WTin, b_in, h_half);

  for (int l = 0; l < LAYERS; ++l) {
    k_gemm_h<<<4 * gmx, 256, 0, stream>>>(h_half, N, WT + (size_t)l * 512 * HID,
                                          b_src + (size_t)l * HID,
                                          b_dst + (size_t)l * HID, fs, fd);
    const bool last = (l == LAYERS - 1);
    k_fused<<<(N + 7) / 8, 256, 0, stream>>>(offs, esrc, perm, fs, fd,
                                             attn + (size_t)l * NHEAD * DOUT,
                                             bias + (size_t)l * HID,
                                             last ? nullptr : h_half,
                                             last ? h_out : nullptr, N);
  }
}